// Round 1
// baseline (6117.457 us; speedup 1.0000x reference)
//
#include <hip/hip_runtime.h>

#define TT 1024
#define BB 256
#define CC 41

__device__ __forceinline__ float sigf(float x) {
    // 1/(1+2^(-x*log2e)) ; safe at both extremes
    float t = __builtin_amdgcn_exp2f(-1.4426950408889634f * x);
    return __builtin_amdgcn_rcpf(1.0f + t);
}
__device__ __forceinline__ float tanhf_fast(float x) {
    // 1 - 2/(2^(2x*log2e)+1) ; safe at both extremes
    float t = __builtin_amdgcn_exp2f(2.8853900817779268f * x);
    return fmaf(-2.0f, __builtin_amdgcn_rcpf(t + 1.0f), 1.0f);
}
__device__ __forceinline__ float lane_bcast(float v, int k) {
    return __uint_as_float(__builtin_amdgcn_readlane(__float_as_uint(v), k));
}

// One (batch row, direction) sequence per block. NT threads, GT=256/NT gates per
// thread; per-thread weight rows live in VGPRs for the whole T loop.
template <int K, int NT>
__global__ __launch_bounds__(NT, 2) void lstm_kernel(
    const float* __restrict__ xin,   // [B,T,K]
    const float* __restrict__ w_ih,  // [2,256,K]
    const float* __restrict__ w_hh,  // [2,256,64]
    const float* __restrict__ bias,  // [2,256]
    float* __restrict__ hout)        // [B,T,128], dir writes its 64-half
{
    constexpr int GT = 256 / NT;
    const int b = blockIdx.x;
    const int dir = blockIdx.y;
    const int tid = threadIdx.x;

    float wx[GT][K];
    float wh[GT][64];
    float bg[GT];
#pragma unroll
    for (int j = 0; j < GT; ++j) {
        const int g = tid + j * NT;
        const float* wr = w_ih + ((size_t)dir * 256 + g) * K;
#pragma unroll
        for (int k = 0; k < K; ++k) wx[j][k] = wr[k];
        const float* hr = w_hh + ((size_t)dir * 256 + g) * 64;
#pragma unroll
        for (int k = 0; k < 64; ++k) wh[j][k] = hr[k];
        bg[j] = bias[dir * 256 + g];
    }

    __shared__ float act[256];
    __shared__ float hcur[64];
    float c = 0.0f;
    if (tid < 64) hcur[tid] = 0.0f;
    __syncthreads();

    const float* xb = xin + (size_t)b * TT * K;
    float* hob = hout + (size_t)b * TT * 128 + dir * 64;

    for (int s = 0; s < TT; ++s) {
        const int t = dir ? (TT - 1 - s) : s;
        const float* xt = xb + (size_t)t * K;

        float ap[4][GT];
#pragma unroll
        for (int j = 0; j < GT; ++j) {
            ap[0][j] = bg[j]; ap[1][j] = 0.f; ap[2][j] = 0.f; ap[3][j] = 0.f;
        }

        // ---- x part: block-uniform loads (scalarizable) ----
        if constexpr ((K & 3) == 0) {
            const float4* xt4 = (const float4*)xt;
#pragma unroll
            for (int q = 0; q < K / 4; ++q) {
                const float4 xv = xt4[q];
#pragma unroll
                for (int j = 0; j < GT; ++j) {
                    ap[0][j] = fmaf(xv.x, wx[j][4 * q + 0], ap[0][j]);
                    ap[1][j] = fmaf(xv.y, wx[j][4 * q + 1], ap[1][j]);
                    ap[2][j] = fmaf(xv.z, wx[j][4 * q + 2], ap[2][j]);
                    ap[3][j] = fmaf(xv.w, wx[j][4 * q + 3], ap[3][j]);
                }
            }
        } else {
#pragma unroll
            for (int k = 0; k < K; ++k) {
                const float xv = xt[k];
#pragma unroll
                for (int j = 0; j < GT; ++j)
                    ap[k & 3][j] = fmaf(xv, wx[j][k], ap[k & 3][j]);
            }
        }

        // ---- h part: readlane broadcast (each wave holds h[0..63] in lanes) ----
        const float hv = hcur[tid & 63];
#pragma unroll
        for (int k = 0; k < 64; ++k) {
            const float hk = lane_bcast(hv, k);
#pragma unroll
            for (int j = 0; j < GT; ++j)
                ap[k & 3][j] = fmaf(hk, wh[j][k], ap[k & 3][j]);
        }

        // ---- activation (gate order i,f,g,o in 64-blocks) ----
#pragma unroll
        for (int j = 0; j < GT; ++j) {
            const float a = (ap[0][j] + ap[1][j]) + (ap[2][j] + ap[3][j]);
            const int g = tid + j * NT;
            act[g] = ((g >> 6) == 2) ? tanhf_fast(a) : sigf(a);
        }
        __syncthreads();

        if (tid < 64) {
            const float iv = act[tid], fv = act[64 + tid];
            const float gv = act[128 + tid], ov = act[192 + tid];
            c = fmaf(fv, c, iv * gv);
            const float h = ov * tanhf_fast(c);
            hcur[tid] = h;
            hob[(size_t)t * 128 + tid] = h;
        }
        __syncthreads();
    }
}

// emissions = feats @ lin_w^T + lin_b ; block tile = 64 (b,t) rows x 41 classes
__global__ __launch_bounds__(256, 2) void emis_kernel(
    const float* __restrict__ feats,  // [B*T,128]
    const float* __restrict__ lw,     // [41,128]
    const float* __restrict__ lb,     // [41]
    float* __restrict__ e)            // [B*T,41]
{
    __shared__ float sf[64 * 132];  // padded rows (bank spread)
    __shared__ float swt[41 * 132];
    const int tid = threadIdx.x;
    const size_t bt0 = (size_t)blockIdx.x * 64;

    const float4* fs = (const float4*)(feats + bt0 * 128);
#pragma unroll
    for (int q = 0; q < 8; ++q) {
        const int idx = tid + q * 256;          // 2048 float4s
        const int row = idx >> 5, col = idx & 31;
        *(float4*)&sf[row * 132 + col * 4] = fs[idx];
    }
    for (int idx = tid; idx < 41 * 32; idx += 256) {
        const int row = idx >> 5, col = idx & 31;
        *(float4*)&swt[row * 132 + col * 4] = ((const float4*)lw)[idx];
    }
    __syncthreads();

    const int btg = tid >> 4;          // 16 groups of 4 rows
    const int cg = tid & 15;           // 16 groups of 3 classes
    const int c0 = cg * 3;
    float acc[4][3];
#pragma unroll
    for (int i = 0; i < 4; ++i)
#pragma unroll
        for (int j = 0; j < 3; ++j) acc[i][j] = 0.f;

    for (int k = 0; k < 128; k += 4) {
        float4 fv[4], wv[3];
#pragma unroll
        for (int i = 0; i < 4; ++i) fv[i] = *(const float4*)&sf[(btg * 4 + i) * 132 + k];
#pragma unroll
        for (int j = 0; j < 3; ++j) {
            const int c = (c0 + j < CC) ? (c0 + j) : (CC - 1);
            wv[j] = *(const float4*)&swt[c * 132 + k];
        }
#pragma unroll
        for (int i = 0; i < 4; ++i)
#pragma unroll
            for (int j = 0; j < 3; ++j) {
                acc[i][j] = fmaf(fv[i].x, wv[j].x, acc[i][j]);
                acc[i][j] = fmaf(fv[i].y, wv[j].y, acc[i][j]);
                acc[i][j] = fmaf(fv[i].z, wv[j].z, acc[i][j]);
                acc[i][j] = fmaf(fv[i].w, wv[j].w, acc[i][j]);
            }
    }
    __syncthreads();
    float* so = sf;  // reuse as [64*41] staging for coalesced store
#pragma unroll
    for (int i = 0; i < 4; ++i)
#pragma unroll
        for (int j = 0; j < 3; ++j) {
            const int c = c0 + j;
            if (c < CC) so[(btg * 4 + i) * CC + c] = acc[i][j] + lb[c];
        }
    __syncthreads();
    float* eo = e + bt0 * CC;
    for (int q = tid; q < 64 * CC; q += 256) eo[q] = so[q];
}

// One wave per batch row; backpointers in LDS; in-kernel backtrace.
__global__ __launch_bounds__(64, 1) void viterbi_kernel(
    const float* __restrict__ e,   // [B,T,41]
    const float* __restrict__ st,  // [41]
    const float* __restrict__ en,  // [41]
    const float* __restrict__ tr,  // [41,41]
    int* __restrict__ out)         // [B,T]
{
    const int b = blockIdx.x;
    const int lane = threadIdx.x;
    __shared__ unsigned char bp[TT][CC];
    __shared__ float sc[2][CC];
    const int c = (lane < CC) ? lane : (CC - 1);
    float trc[CC];
#pragma unroll
    for (int p = 0; p < CC; ++p) trc[p] = tr[p * CC + c];

    const float* eb = e + (size_t)b * TT * CC;
    const float NEG = -3.0e38f;
    if (lane < CC) sc[0][lane] = st[lane] + eb[lane];
    __syncthreads();

    for (int t = 1; t < TT; ++t) {
        const float* scp = sc[(t - 1) & 1];
        float best = NEG;
        int bi = 0;
#pragma unroll
        for (int p = 0; p < CC; ++p) {
            const float v = scp[p] + trc[p];
            if (v > best) { best = v; bi = p; }   // strict > : first-index ties
        }
        if (lane < CC) {
            sc[t & 1][lane] = best + eb[(size_t)t * CC + lane];
            bp[t][lane] = (unsigned char)bi;
        }
        __syncthreads();
    }

    float fin = (lane < CC) ? sc[(TT - 1) & 1][lane] + en[lane] : NEG;
    int idx = lane;
#pragma unroll
    for (int off = 32; off; off >>= 1) {
        const float v2 = __shfl_down(fin, off, 64);
        const int i2 = __shfl_down(idx, off, 64);
        if (v2 > fin || (v2 == fin && i2 < idx)) { fin = v2; idx = i2; }
    }
    int tag = __shfl(idx, 0, 64);
    if (lane == 0) {
        int* ob = out + (size_t)b * TT;
        ob[TT - 1] = tag;
        for (int t = TT - 1; t >= 1; --t) {
            tag = bp[t][tag];
            ob[t - 1] = tag;
        }
    }
}

extern "C" void kernel_launch(void* const* d_in, const int* in_sizes, int n_in,
                              void* d_out, int out_size, void* d_ws, size_t ws_size,
                              hipStream_t stream) {
    const float* x       = (const float*)d_in[0];   // [B,T,39]
    const float* w_ih_l0 = (const float*)d_in[1];   // [2,256,39]
    const float* w_hh_l0 = (const float*)d_in[2];   // [2,256,64]
    const float* b_l0    = (const float*)d_in[3];   // [2,256]
    const float* w_ih_r  = (const float*)d_in[4];   // [2,2,256,128]
    const float* w_hh_r  = (const float*)d_in[5];   // [2,2,256,64]
    const float* b_r     = (const float*)d_in[6];   // [2,2,256]
    const float* lin_w   = (const float*)d_in[7];   // [41,128]
    const float* lin_b   = (const float*)d_in[8];   // [41]
    const float* crf_s   = (const float*)d_in[9];   // [41]
    const float* crf_e   = (const float*)d_in[10];  // [41]
    const float* crf_t   = (const float*)d_in[11];  // [41,41]
    int* out = (int*)d_out;

    float* buf0 = (float*)d_ws;                         // [B,T,128] = 128 MiB
    float* buf1 = buf0 + (size_t)BB * TT * 128;         // [B,T,128] = 128 MiB

    dim3 grid(BB, 2);
    // layer 0 (input dim 39): buf0 <- x
    lstm_kernel<39, 128><<<grid, 128, 0, stream>>>(x, w_ih_l0, w_hh_l0, b_l0, buf0);
    // layer 1: buf1 <- buf0
    lstm_kernel<128, 256><<<grid, 256, 0, stream>>>(buf0, w_ih_r, w_hh_r, b_r, buf1);
    // layer 2: buf0 <- buf1
    lstm_kernel<128, 256><<<grid, 256, 0, stream>>>(
        buf1, w_ih_r + 2 * 256 * 128, w_hh_r + 2 * 256 * 64, b_r + 2 * 256, buf0);
    // emissions: buf1 <- buf0 (L2 output), [B*T,41]
    emis_kernel<<<BB * TT / 64, 256, 0, stream>>>(buf0, lin_w, lin_b, buf1);
    // viterbi + backtrace
    viterbi_kernel<<<BB, 64, 0, stream>>>(buf1, crf_s, crf_e, crf_t, out);
}